// Round 16
// baseline (184.243 us; speedup 1.0000x reference)
//
#include <hip/hip_runtime.h>
#include <math.h>

// NLM S=21, 256x256x3, reflect padding. Round 16 = R15 + launch-side fusion:
// - fast sqrt (__builtin_amdgcn_sqrtf = single v_sqrt_f32; fp16 noise floor
//   dominates anyway)
// - finalize FUSED into nlm_main: per-tile completion counter (device-scope
//   atomic + __threadfence release/acquire); last of a tile's 8 blocks reduces
//   the 8 partial groups and writes the clipped output -> 1 kernel total
// - incremental du/dv (no int division in hot loop)
// - hot loop otherwise verbatim R15: 512-thr blocks, 8 wave-streams/tile,
//   2 blocks/CU, barrier-free h+v per wave, packed fp16 tap accumulation

#define IMG 256
#define NPIX (IMG * IMG)
#define TILE 32
#define GR 52      // window-grid dim
#define YD 72      // staged Y rows/cols
#define YSTR 78    // Yreg row stride in halves (39 dwords, odd -> full bank spread)
#define HST 54     // hsT t-stride in halves (27 dwords, odd -> full bank spread)
#define NOFF 441
#define NGB 8      // offset groups (grid.y); 8 wave-streams each -> 64 streams
#define NTHR 512

typedef __attribute__((ext_vector_type(4))) _Float16 half4;
typedef __attribute__((ext_vector_type(2))) _Float16 half2_t;

#if __has_builtin(__builtin_amdgcn_fdot2)
#define FDOT2(a, b, c) __builtin_amdgcn_fdot2((a), (b), (c), false)
#else
#define FDOT2(a, b, c) ((c) + (float)(a).x * (float)(b).x + (float)(a).y * (float)(b).y)
#endif

#if __has_builtin(__builtin_amdgcn_sqrtf)
#define ASQRT(x) __builtin_amdgcn_sqrtf(x)
#else
#define ASQRT(x) sqrtf(x)
#endif

__device__ __forceinline__ int refl(int t) {
    t = t < 0 ? -t : t;             // valid for t in [-255, 510]
    return t > 255 ? 510 - t : t;
}

template <bool DIRECT>
__global__ __launch_bounds__(NTHR, 4)
void nlm_main(const float* __restrict__ rgb, const float* __restrict__ hptr,
              float4* __restrict__ partials, unsigned int* __restrict__ counters,
              float* __restrict__ out)
{
    __shared__ __align__(16) _Float16 Yreg[YD][YSTR];      // 11232 B
    __shared__ __align__(16) _Float16 Creg4[GR][GR][4];    // 21632 B (epilogue scratch too)
    __shared__ __align__(16) _Float16 hsT[8][TILE][HST];   // 27648 B (private per wave)
    __shared__ unsigned char cjTab[21][GR];                //  1092 B
    __shared__ unsigned int doneCnt;
    // total ~61.7 KB -> 2 blocks/CU (16 waves/CU)

    const int tid = threadIdx.x;
    const int tj = ((int)blockIdx.x & 7) * TILE;
    const int ti = ((int)blockIdx.x >> 3) * TILE;

    const int Ybi = min(max(ti - 20, 0), IMG - YD);
    const int Ybj = min(max(tj - 20, 0), IMG - YD);
    const bool interior = (ti >= 20) && (ti + 51 <= 255) && (tj >= 20) && (tj + 51 <= 255);

    // ---- stage Y (clipped luminance, fp16) ----
    for (int idx = tid; idx < YD * YD; idx += NTHR) {
        int a = idx / YD, b = idx - a * YD;
        int g = (Ybi + a) * IMG + (Ybj + b);
        float r  = fminf(fmaxf(rgb[g], 0.f), 1.f);
        float gg = fminf(fmaxf(rgb[NPIX + g], 0.f), 1.f);
        float bb = fminf(fmaxf(rgb[2 * NPIX + g], 0.f), 1.f);
        Yreg[a][b] = (_Float16)(0.299f * r + 0.587f * gg + 0.114f * bb);
    }
    // ---- stage RGB1 taps at window-grid coords (UNclipped rgb; w-slot = 1) ----
    for (int idx = tid; idx < GR * GR; idx += NTHR) {
        int t = idx / GR, b = idx - t * GR;
        int g = refl(ti - 10 + t) * IMG + refl(tj - 10 + b);
        half4 c;
        c.x = (_Float16)rgb[g];
        c.y = (_Float16)rgb[NPIX + g];
        c.z = (_Float16)rgb[2 * NPIX + g];
        c.w = (_Float16)1.f;                   // weight accumulator partner
        *(half4*)&Creg4[t][b][0] = c;
    }
    // ---- col refl maps for all dv (edge tiles) ----
    if (!interior) {
        for (int idx = tid; idx < 21 * GR; idx += NTHR) {
            int d = idx / GR, c = idx - d * GR;
            cjTab[d][c] = (unsigned char)(refl(refl(tj - 10 + c) + (d - 10)) - Ybj);
        }
    }
    __syncthreads();   // staging complete

    const int lane = tid & 63;
    const int wv   = tid >> 6;               // wave id 0..7
    const bool hact = lane < GR;

    // ---- persistent y0 row (offset-invariant), 13 VGPRs ----
    half2_t y0h[26];
    if (hact) {
        if (interior) {
            const half2_t* q0 = (const half2_t*)&Yreg[lane + 10][10];
            #pragma unroll
            for (int i = 0; i < 26; ++i) y0h[i] = q0[i];
        } else {
            const _Float16* Y0row = &Yreg[refl(ti - 10 + lane) - Ybi][0];
            const unsigned char* cj0 = &cjTab[10][0];
            #pragma unroll
            for (int i = 0; i < 26; ++i) {
                half2_t v;
                v.x = Y0row[cj0[2 * i]];
                v.y = Y0row[cj0[2 * i + 1]];
                y0h[i] = v;
            }
        }
    }

    const float hv = fmaxf(hptr[0], 0.f);
    const float negI = -1.0f / (hv + 1e-8f);

    // v decomposition: lane -> (col pb, 16-row strip)
    const int pb  = lane & 31;
    const int s16 = (lane >> 5) << 4;        // 0 or 16

    half2_t accRG[16], accBW[16];            // packed fp16 accumulators (32 VGPRs)
    #pragma unroll
    for (int k = 0; k < 16; ++k) {
        accRG[k].x = (_Float16)0.f; accRG[k].y = (_Float16)0.f;
        accBW[k].x = (_Float16)0.f; accBW[k].y = (_Float16)0.f;
    }

    half2_t one; one.x = (_Float16)1.f; one.y = (_Float16)1.f;

    // ---- barrier-free offset loop: this wave owns offsets o = base + 64k ----
    const int o0 = (int)blockIdx.y * 8 + wv;
    int du = o0 / 21 - 10;
    int dv = o0 % 21 - 10;
    for (int o = o0; o < NOFF; o += 64) {
        // ===== h-phase: lane = window row t, writes 32 col-sums to own strip =====
        if (hact) {
            const int t = lane;
            half2_t ff[26];
            if (interior) {
                if ((dv & 1) == 0) {
                    const half2_t* q1 = (const half2_t*)&Yreg[t + 10 + du][10 + dv];
                    #pragma unroll
                    for (int i = 0; i < 26; ++i) {
                        half2_t d2 = y0h[i] - q1[i];
                        ff[i] = d2 * d2;
                    }
                } else {
                    const half2_t* q1 = (const half2_t*)&Yreg[t + 10 + du][10 + dv - 1];
                    half2_t prev = q1[0];
                    #pragma unroll
                    for (int i = 0; i < 26; ++i) {
                        half2_t cur = q1[i + 1];
                        half2_t b; b.x = prev.y; b.y = cur.x;
                        half2_t d2 = y0h[i] - b;
                        ff[i] = d2 * d2;
                        prev = cur;
                    }
                }
            } else {
                const unsigned int* cw = (const unsigned int*)&cjTab[dv + 10][0];
                const _Float16* Y1row = &Yreg[refl(refl(ti - 10 + t) + du) - Ybi][0];
                #pragma unroll
                for (int i = 0; i < 26; ++i) {
                    unsigned int w0 = cw[i >> 1];
                    int sh = (i & 1) * 16;
                    _Float16 a0 = Y1row[(w0 >> sh) & 0xffu];
                    _Float16 a1 = Y1row[(w0 >> (sh + 8)) & 0xffu];
                    half2_t yv; yv.x = a0; yv.y = a1;
                    half2_t d2 = y0h[i] - yv;
                    ff[i] = d2 * d2;
                }
            }
            // two independent seeds: k=0 (f0..f20), k=16 (f16..f36)
            float s0f = 0.f, s1f = 0.f;
            #pragma unroll
            for (int i = 0; i < 10; ++i) s0f = FDOT2(ff[i], one, s0f);
            s0f += (float)ff[10].x;
            #pragma unroll
            for (int i = 8; i < 18; ++i) s1f = FDOT2(ff[i], one, s1f);
            s1f += (float)ff[18].x;
            _Float16 sA = (_Float16)s0f;
            _Float16 sB = (_Float16)s1f;
            hsT[wv][0][t]  = sA;
            hsT[wv][16][t] = sB;
            // two independent 15-step fp16 chains
            #pragma unroll
            for (int k = 1; k < 16; ++k) {
                {
                    int ja = 20 + k, jb = k - 1;
                    _Float16 fa = (ja & 1) ? ff[ja >> 1].y : ff[ja >> 1].x;
                    _Float16 fb = (jb & 1) ? ff[jb >> 1].y : ff[jb >> 1].x;
                    sA += (_Float16)(fa - fb);
                    hsT[wv][k][t] = sA;
                }
                {
                    int ja = 36 + k, jb = 15 + k;
                    _Float16 fa = (ja & 1) ? ff[ja >> 1].y : ff[ja >> 1].x;
                    _Float16 fb = (jb & 1) ? ff[jb >> 1].y : ff[jb >> 1].x;
                    sB += (_Float16)(fa - fb);
                    hsT[wv][16 + k][t] = sB;
                }
            }
        }

        // ===== v-phase: same wave, in-order DS -> no barrier needed =====
        {
            const half2_t* col2 = (const half2_t*)&hsT[wv][pb][s16];
            half2_t w2[18];                  // rows s16 .. s16+35
            #pragma unroll
            for (int i = 0; i < 18; ++i) w2[i] = col2[i];

            float vs0 = 0.f, vs1 = 0.f;
            #pragma unroll
            for (int i = 0; i < 10; ++i) vs0 = FDOT2(w2[i], one, vs0);
            vs0 += (float)w2[10].x;
            #pragma unroll
            for (int i = 4; i < 14; ++i) vs1 = FDOT2(w2[i], one, vs1);
            vs1 += (float)w2[14].x;

            float vss[16];
            vss[0] = vs0;
            vss[8] = vs1;
            #pragma unroll
            for (int k = 0; k < 7; ++k) {
                {   // chain A: vss[1..7]
                    int ja = 21 + k, jb = k;
                    _Float16 fa = (ja & 1) ? w2[ja >> 1].y : w2[ja >> 1].x;
                    _Float16 fb = (jb & 1) ? w2[jb >> 1].y : w2[jb >> 1].x;
                    vss[k + 1] = vss[k] + (float)(_Float16)(fa - fb);
                }
                {   // chain B: vss[9..15]
                    int ja = 29 + k, jb = 8 + k;
                    _Float16 fa = (ja & 1) ? w2[ja >> 1].y : w2[ja >> 1].x;
                    _Float16 fb = (jb & 1) ? w2[jb >> 1].y : w2[jb >> 1].x;
                    vss[k + 9] = vss[k + 8] + (float)(_Float16)(fa - fb);
                }
            }

            const int cr = s16 + 10 + du;
            const int cc = pb + 10 + dv;
            #pragma unroll
            for (int k = 0; k < 16; ++k) {
                float dist = ASQRT(fmaxf(vss[k], 0.f));
                float w = __expf(dist * negI);
                _Float16 wh = (_Float16)w;
                half2_t w2v; w2v.x = wh; w2v.y = wh;
                const half2_t* cp = (const half2_t*)&Creg4[cr + k][cc][0];
                half2_t cRG = cp[0];         // (R, G)
                half2_t cBW = cp[1];         // (B, 1)
                accRG[k] = w2v * cRG + accRG[k];   // v_pk_fma_f16
                accBW[k] = w2v * cBW + accBW[k];
            }
        }

        // advance offset by 64 (= 3*21 + 1)
        du += 3; dv += 1;
        if (dv > 10) { dv -= 21; du += 1; }
    }

    // ---- epilogue: merge 8 wave-streams via reused Creg LDS ----
    __syncthreads();                          // all taps consumed; Creg4 reusable
    float4* scratch = (float4*)&Creg4[0][0][0];   // 1024 x float4 = 16384 B
    #pragma unroll
    for (int w = 0; w < 8; ++w) {
        if (wv == w) {
            #pragma unroll
            for (int k = 0; k < 16; ++k) {
                int px = (s16 + k) * 32 + pb;
                float4 v = make_float4((float)accRG[k].x, (float)accRG[k].y,
                                       (float)accBW[k].x, (float)accBW[k].y);
                if (w == 0) scratch[px] = v;
                else {
                    float4 a = scratch[px];
                    scratch[px] = make_float4(a.x + v.x, a.y + v.y, a.z + v.z, a.w + v.w);
                }
            }
        }
        __syncthreads();
    }
    // ---- store this group's partials, coalesced ----
    for (int i = tid; i < TILE * TILE; i += NTHR) {
        float4 v = scratch[i];
        int gpix = (ti + (i >> 5)) * IMG + (tj + (i & 31));
        if (DIRECT) {
            partials[(size_t)blockIdx.y * NPIX + gpix] = v;
        } else {
            float* p = (float*)&partials[gpix];
            atomicAdd(p + 0, v.x);
            atomicAdd(p + 1, v.y);
            atomicAdd(p + 2, v.z);
            atomicAdd(p + 3, v.w);
        }
    }

    if (DIRECT) {
        // ---- fused finalize: last of this tile's 8 blocks reduces + writes out ----
        __threadfence();                      // release this block's partials
        if (tid == 0) doneCnt = atomicAdd(&counters[blockIdx.x], 1u);
        __syncthreads();
        if (doneCnt == NGB - 1) {
            __threadfence();                  // acquire other blocks' partials
            for (int i = tid; i < TILE * TILE; i += NTHR) {
                int gpix = (ti + (i >> 5)) * IMG + (tj + (i & 31));
                float r = 0.f, g = 0.f, b = 0.f, w = 0.f;
                #pragma unroll
                for (int gg = 0; gg < NGB; ++gg) {
                    float4 p = partials[(size_t)gg * NPIX + gpix];
                    r += p.x; g += p.y; b += p.z; w += p.w;
                }
                float inv = 1.0f / w;         // sum(w) >= 1 (self offset)
                out[gpix]            = fminf(fmaxf(r * inv, 0.f), 1.f);
                out[NPIX + gpix]     = fminf(fmaxf(g * inv, 0.f), 1.f);
                out[2 * NPIX + gpix] = fminf(fmaxf(b * inv, 0.f), 1.f);
            }
        }
    }
}

__global__ __launch_bounds__(256)
void nlm_finalize1(const float4* __restrict__ partials, float* __restrict__ out)
{
    int idx = blockIdx.x * blockDim.x + threadIdx.x;
    float4 p = partials[idx];
    float inv = 1.0f / p.w;
    out[idx]            = fminf(fmaxf(p.x * inv, 0.f), 1.f);
    out[NPIX + idx]     = fminf(fmaxf(p.y * inv, 0.f), 1.f);
    out[2 * NPIX + idx] = fminf(fmaxf(p.z * inv, 0.f), 1.f);
}

extern "C" void kernel_launch(void* const* d_in, const int* in_sizes, int n_in,
                              void* d_out, int out_size, void* d_ws, size_t ws_size,
                              hipStream_t stream) {
    (void)in_sizes; (void)n_in; (void)out_size;
    const float* rgb  = (const float*)d_in[0];
    const float* hptr = (const float*)d_in[1];
    float* out = (float*)d_out;
    float4* partials = (float4*)d_ws;
    unsigned int* counters = (unsigned int*)((char*)d_ws + (size_t)NGB * NPIX * sizeof(float4));

    const bool direct = ws_size >= (size_t)NGB * NPIX * sizeof(float4) + 4096;  // ~8.4 MB
    dim3 grid(64, NGB);   // 512 blocks = exactly 2 blocks/CU
    if (direct) {
        (void)hipMemsetAsync(counters, 0, 64 * sizeof(unsigned int), stream);
        nlm_main<true><<<grid, NTHR, 0, stream>>>(rgb, hptr, partials, counters, out);
    } else {
        (void)hipMemsetAsync(partials, 0, (size_t)NPIX * sizeof(float4), stream);
        nlm_main<false><<<grid, NTHR, 0, stream>>>(rgb, hptr, partials, counters, out);
        nlm_finalize1<<<NPIX / 256, 256, 0, stream>>>(partials, out);
    }
}

// Round 17
// 99.799 us; speedup vs baseline: 1.8462x; 1.8462x over previous
//
#include <hip/hip_runtime.h>
#include <math.h>

// NLM S=21, 256x256x3, reflect padding. Round 17 = R15 champion + isolated wins:
// - ASQRT: __builtin_amdgcn_sqrtf (single v_sqrt_f32; fp16 noise floor dominates)
// - incremental du/dv (stride 64 = 3*21+1; no int division in hot loop)
// - NO fused finalize (R16's __threadfence L2-flush regression reverted)
// - 512-thr blocks, 8 wave-streams/tile, 2 blocks/CU, barrier-free h+v per wave,
//   packed fp16 tap accumulation, direct-store partials + unrolled finalize

#define IMG 256
#define NPIX (IMG * IMG)
#define TILE 32
#define GR 52      // window-grid dim
#define YD 72      // staged Y rows/cols
#define YSTR 78    // Yreg row stride in halves (39 dwords, odd -> full bank spread)
#define HST 54     // hsT t-stride in halves (27 dwords, odd -> full bank spread)
#define NOFF 441
#define NGB 8      // offset groups (grid.y); 8 wave-streams each -> 64 streams
#define NTHR 512

typedef __attribute__((ext_vector_type(4))) _Float16 half4;
typedef __attribute__((ext_vector_type(2))) _Float16 half2_t;

#if __has_builtin(__builtin_amdgcn_fdot2)
#define FDOT2(a, b, c) __builtin_amdgcn_fdot2((a), (b), (c), false)
#else
#define FDOT2(a, b, c) ((c) + (float)(a).x * (float)(b).x + (float)(a).y * (float)(b).y)
#endif

#if __has_builtin(__builtin_amdgcn_sqrtf)
#define ASQRT(x) __builtin_amdgcn_sqrtf(x)
#else
#define ASQRT(x) sqrtf(x)
#endif

__device__ __forceinline__ int refl(int t) {
    t = t < 0 ? -t : t;             // valid for t in [-255, 510]
    return t > 255 ? 510 - t : t;
}

template <bool DIRECT>
__global__ __launch_bounds__(NTHR, 4)
void nlm_main(const float* __restrict__ rgb, const float* __restrict__ hptr,
              float4* __restrict__ partials)
{
    __shared__ __align__(16) _Float16 Yreg[YD][YSTR];      // 11232 B
    __shared__ __align__(16) _Float16 Creg4[GR][GR][4];    // 21632 B (epilogue scratch too)
    __shared__ __align__(16) _Float16 hsT[8][TILE][HST];   // 27648 B (private per wave)
    __shared__ unsigned char cjTab[21][GR];                //  1092 B
    // total 61604 B -> 2 blocks/CU (16 waves/CU)

    const int tid = threadIdx.x;
    const int tj = ((int)blockIdx.x & 7) * TILE;
    const int ti = ((int)blockIdx.x >> 3) * TILE;

    const int Ybi = min(max(ti - 20, 0), IMG - YD);
    const int Ybj = min(max(tj - 20, 0), IMG - YD);
    const bool interior = (ti >= 20) && (ti + 51 <= 255) && (tj >= 20) && (tj + 51 <= 255);

    // ---- stage Y (clipped luminance, fp16) ----
    for (int idx = tid; idx < YD * YD; idx += NTHR) {
        int a = idx / YD, b = idx - a * YD;
        int g = (Ybi + a) * IMG + (Ybj + b);
        float r  = fminf(fmaxf(rgb[g], 0.f), 1.f);
        float gg = fminf(fmaxf(rgb[NPIX + g], 0.f), 1.f);
        float bb = fminf(fmaxf(rgb[2 * NPIX + g], 0.f), 1.f);
        Yreg[a][b] = (_Float16)(0.299f * r + 0.587f * gg + 0.114f * bb);
    }
    // ---- stage RGB1 taps at window-grid coords (UNclipped rgb; w-slot = 1) ----
    for (int idx = tid; idx < GR * GR; idx += NTHR) {
        int t = idx / GR, b = idx - t * GR;
        int g = refl(ti - 10 + t) * IMG + refl(tj - 10 + b);
        half4 c;
        c.x = (_Float16)rgb[g];
        c.y = (_Float16)rgb[NPIX + g];
        c.z = (_Float16)rgb[2 * NPIX + g];
        c.w = (_Float16)1.f;                   // weight accumulator partner
        *(half4*)&Creg4[t][b][0] = c;
    }
    // ---- col refl maps for all dv (edge tiles) ----
    if (!interior) {
        for (int idx = tid; idx < 21 * GR; idx += NTHR) {
            int d = idx / GR, c = idx - d * GR;
            cjTab[d][c] = (unsigned char)(refl(refl(tj - 10 + c) + (d - 10)) - Ybj);
        }
    }
    __syncthreads();   // staging complete — last barrier before epilogue

    const int lane = tid & 63;
    const int wv   = tid >> 6;               // wave id 0..7
    const bool hact = lane < GR;

    // ---- persistent y0 row (offset-invariant), 13 VGPRs ----
    half2_t y0h[26];
    if (hact) {
        if (interior) {
            const half2_t* q0 = (const half2_t*)&Yreg[lane + 10][10];
            #pragma unroll
            for (int i = 0; i < 26; ++i) y0h[i] = q0[i];
        } else {
            const _Float16* Y0row = &Yreg[refl(ti - 10 + lane) - Ybi][0];
            const unsigned char* cj0 = &cjTab[10][0];
            #pragma unroll
            for (int i = 0; i < 26; ++i) {
                half2_t v;
                v.x = Y0row[cj0[2 * i]];
                v.y = Y0row[cj0[2 * i + 1]];
                y0h[i] = v;
            }
        }
    }

    const float hv = fmaxf(hptr[0], 0.f);
    const float negI = -1.0f / (hv + 1e-8f);

    // v decomposition: lane -> (col pb, 16-row strip)
    const int pb  = lane & 31;
    const int s16 = (lane >> 5) << 4;        // 0 or 16

    half2_t accRG[16], accBW[16];            // packed fp16 accumulators (32 VGPRs)
    #pragma unroll
    for (int k = 0; k < 16; ++k) {
        accRG[k].x = (_Float16)0.f; accRG[k].y = (_Float16)0.f;
        accBW[k].x = (_Float16)0.f; accBW[k].y = (_Float16)0.f;
    }

    half2_t one; one.x = (_Float16)1.f; one.y = (_Float16)1.f;

    // ---- barrier-free offset loop: this wave owns offsets o = base + 64k ----
    const int o0 = (int)blockIdx.y * 8 + wv;
    int du = o0 / 21 - 10;
    int dv = o0 % 21 - 10;
    for (int o = o0; o < NOFF; o += 64) {
        // ===== h-phase: lane = window row t, writes 32 col-sums to own strip =====
        if (hact) {
            const int t = lane;
            half2_t ff[26];
            if (interior) {
                if ((dv & 1) == 0) {
                    const half2_t* q1 = (const half2_t*)&Yreg[t + 10 + du][10 + dv];
                    #pragma unroll
                    for (int i = 0; i < 26; ++i) {
                        half2_t d2 = y0h[i] - q1[i];
                        ff[i] = d2 * d2;
                    }
                } else {
                    const half2_t* q1 = (const half2_t*)&Yreg[t + 10 + du][10 + dv - 1];
                    half2_t prev = q1[0];
                    #pragma unroll
                    for (int i = 0; i < 26; ++i) {
                        half2_t cur = q1[i + 1];
                        half2_t b; b.x = prev.y; b.y = cur.x;
                        half2_t d2 = y0h[i] - b;
                        ff[i] = d2 * d2;
                        prev = cur;
                    }
                }
            } else {
                const unsigned int* cw = (const unsigned int*)&cjTab[dv + 10][0];
                const _Float16* Y1row = &Yreg[refl(refl(ti - 10 + t) + du) - Ybi][0];
                #pragma unroll
                for (int i = 0; i < 26; ++i) {
                    unsigned int w0 = cw[i >> 1];
                    int sh = (i & 1) * 16;
                    _Float16 a0 = Y1row[(w0 >> sh) & 0xffu];
                    _Float16 a1 = Y1row[(w0 >> (sh + 8)) & 0xffu];
                    half2_t yv; yv.x = a0; yv.y = a1;
                    half2_t d2 = y0h[i] - yv;
                    ff[i] = d2 * d2;
                }
            }
            // two independent seeds: k=0 (f0..f20), k=16 (f16..f36)
            float s0f = 0.f, s1f = 0.f;
            #pragma unroll
            for (int i = 0; i < 10; ++i) s0f = FDOT2(ff[i], one, s0f);
            s0f += (float)ff[10].x;
            #pragma unroll
            for (int i = 8; i < 18; ++i) s1f = FDOT2(ff[i], one, s1f);
            s1f += (float)ff[18].x;
            _Float16 sA = (_Float16)s0f;
            _Float16 sB = (_Float16)s1f;
            hsT[wv][0][t]  = sA;
            hsT[wv][16][t] = sB;
            // two independent 15-step fp16 chains
            #pragma unroll
            for (int k = 1; k < 16; ++k) {
                {
                    int ja = 20 + k, jb = k - 1;
                    _Float16 fa = (ja & 1) ? ff[ja >> 1].y : ff[ja >> 1].x;
                    _Float16 fb = (jb & 1) ? ff[jb >> 1].y : ff[jb >> 1].x;
                    sA += (_Float16)(fa - fb);
                    hsT[wv][k][t] = sA;
                }
                {
                    int ja = 36 + k, jb = 15 + k;
                    _Float16 fa = (ja & 1) ? ff[ja >> 1].y : ff[ja >> 1].x;
                    _Float16 fb = (jb & 1) ? ff[jb >> 1].y : ff[jb >> 1].x;
                    sB += (_Float16)(fa - fb);
                    hsT[wv][16 + k][t] = sB;
                }
            }
        }

        // ===== v-phase: same wave, in-order DS -> no barrier needed =====
        {
            const half2_t* col2 = (const half2_t*)&hsT[wv][pb][s16];
            half2_t w2[18];                  // rows s16 .. s16+35
            #pragma unroll
            for (int i = 0; i < 18; ++i) w2[i] = col2[i];

            float vs0 = 0.f, vs1 = 0.f;
            #pragma unroll
            for (int i = 0; i < 10; ++i) vs0 = FDOT2(w2[i], one, vs0);
            vs0 += (float)w2[10].x;
            #pragma unroll
            for (int i = 4; i < 14; ++i) vs1 = FDOT2(w2[i], one, vs1);
            vs1 += (float)w2[14].x;

            float vss[16];
            vss[0] = vs0;
            vss[8] = vs1;
            #pragma unroll
            for (int k = 0; k < 7; ++k) {
                {   // chain A: vss[1..7]
                    int ja = 21 + k, jb = k;
                    _Float16 fa = (ja & 1) ? w2[ja >> 1].y : w2[ja >> 1].x;
                    _Float16 fb = (jb & 1) ? w2[jb >> 1].y : w2[jb >> 1].x;
                    vss[k + 1] = vss[k] + (float)(_Float16)(fa - fb);
                }
                {   // chain B: vss[9..15]
                    int ja = 29 + k, jb = 8 + k;
                    _Float16 fa = (ja & 1) ? w2[ja >> 1].y : w2[ja >> 1].x;
                    _Float16 fb = (jb & 1) ? w2[jb >> 1].y : w2[jb >> 1].x;
                    vss[k + 9] = vss[k + 8] + (float)(_Float16)(fa - fb);
                }
            }

            const int cr = s16 + 10 + du;
            const int cc = pb + 10 + dv;
            #pragma unroll
            for (int k = 0; k < 16; ++k) {
                float dist = ASQRT(fmaxf(vss[k], 0.f));
                float w = __expf(dist * negI);
                _Float16 wh = (_Float16)w;
                half2_t w2v; w2v.x = wh; w2v.y = wh;
                const half2_t* cp = (const half2_t*)&Creg4[cr + k][cc][0];
                half2_t cRG = cp[0];         // (R, G)
                half2_t cBW = cp[1];         // (B, 1)
                accRG[k] = w2v * cRG + accRG[k];   // v_pk_fma_f16
                accBW[k] = w2v * cBW + accBW[k];
            }
        }

        // advance offset by 64 (= 3*21 + 1)
        du += 3; dv += 1;
        if (dv > 10) { dv -= 21; du += 1; }
    }

    // ---- epilogue: merge 8 wave-streams via reused Creg LDS ----
    __syncthreads();                          // all taps consumed; Creg4 reusable
    float4* scratch = (float4*)&Creg4[0][0][0];   // 1024 x float4 = 16384 B
    #pragma unroll
    for (int w = 0; w < 8; ++w) {
        if (wv == w) {
            #pragma unroll
            for (int k = 0; k < 16; ++k) {
                int px = (s16 + k) * 32 + pb;
                float4 v = make_float4((float)accRG[k].x, (float)accRG[k].y,
                                       (float)accBW[k].x, (float)accBW[k].y);
                if (w == 0) scratch[px] = v;
                else {
                    float4 a = scratch[px];
                    scratch[px] = make_float4(a.x + v.x, a.y + v.y, a.z + v.z, a.w + v.w);
                }
            }
        }
        __syncthreads();
    }
    // ---- store: one float4 per pixel, coalesced ----
    for (int i = tid; i < TILE * TILE; i += NTHR) {
        float4 v = scratch[i];
        int gpix = (ti + (i >> 5)) * IMG + (tj + (i & 31));
        if (DIRECT) {
            partials[(size_t)blockIdx.y * NPIX + gpix] = v;
        } else {
            float* p = (float*)&partials[gpix];
            atomicAdd(p + 0, v.x);
            atomicAdd(p + 1, v.y);
            atomicAdd(p + 2, v.z);
            atomicAdd(p + 3, v.w);
        }
    }
}

template <int NGT>
__global__ __launch_bounds__(256)
void nlm_finalize(const float4* __restrict__ partials, float* __restrict__ out)
{
    int idx = blockIdx.x * blockDim.x + threadIdx.x;
    float r = 0.f, g = 0.f, b = 0.f, w = 0.f;
    #pragma unroll
    for (int gg = 0; gg < NGT; ++gg) {
        float4 p = partials[(size_t)gg * NPIX + idx];
        r += p.x; g += p.y; b += p.z; w += p.w;
    }
    float inv = 1.0f / w;   // sum(w) >= 1 (self offset contributes exp(0))
    out[idx]            = fminf(fmaxf(r * inv, 0.f), 1.f);
    out[NPIX + idx]     = fminf(fmaxf(g * inv, 0.f), 1.f);
    out[2 * NPIX + idx] = fminf(fmaxf(b * inv, 0.f), 1.f);
}

extern "C" void kernel_launch(void* const* d_in, const int* in_sizes, int n_in,
                              void* d_out, int out_size, void* d_ws, size_t ws_size,
                              hipStream_t stream) {
    (void)in_sizes; (void)n_in; (void)out_size;
    const float* rgb  = (const float*)d_in[0];
    const float* hptr = (const float*)d_in[1];
    float* out = (float*)d_out;
    float4* partials = (float4*)d_ws;

    const bool direct = ws_size >= (size_t)NGB * NPIX * sizeof(float4);  // 8.4 MB
    dim3 grid(64, NGB);   // 512 blocks = exactly 2 blocks/CU
    if (direct) {
        nlm_main<true><<<grid, NTHR, 0, stream>>>(rgb, hptr, partials);
        nlm_finalize<NGB><<<NPIX / 256, 256, 0, stream>>>(partials, out);
    } else {
        (void)hipMemsetAsync(partials, 0, (size_t)NPIX * sizeof(float4), stream);
        nlm_main<false><<<grid, NTHR, 0, stream>>>(rgb, hptr, partials);
        nlm_finalize<1><<<NPIX / 256, 256, 0, stream>>>(partials, out);
    }
}